// Round 1
// baseline (746.755 us; speedup 1.0000x reference)
//
#include <hip/hip_runtime.h>
#include <cmath>

// SSM (Mamba-1 style) forward, f32 correctness baseline.
// Pipeline: rmsnorm -> in_proj GEMM -> silu gate -> depthwise conv ->
//           dt GEMM(+bias+softplus) -> B/C proj -> chunk-parallel exact scan (3 kernels) ->
//           out_proj GEMM.

#define SEQ    1024
#define BATCH  2
#define DMODEL 1024
#define DINNER 2048
#define DSTATE 16
#define NTOK   (BATCH * SEQ)
#define NCHUNK 32
#define CLEN   32

__device__ __forceinline__ float softplus_f(float x) {
  return (x > 20.f) ? x : log1pf(__expf(x));
}

__global__ __launch_bounds__(256) void init_aneg_k(const float* __restrict__ A_log,
                                                   float* __restrict__ Aneg) {
  int i = blockIdx.x * 256 + threadIdx.x;
  Aneg[i] = -__expf(A_log[i]);
}

__global__ __launch_bounds__(256) void rmsnorm_k(const float* __restrict__ x,
                                                 const float* __restrict__ w,
                                                 float* __restrict__ xn) {
  int row = blockIdx.x, tid = threadIdx.x;
  const float4 v = *(const float4*)(x + (size_t)row * DMODEL + tid * 4);
  float ss = v.x * v.x + v.y * v.y + v.z * v.z + v.w * v.w;
#pragma unroll
  for (int off = 32; off > 0; off >>= 1) ss += __shfl_down(ss, off);
  __shared__ float red[4];
  if ((tid & 63) == 0) red[tid >> 6] = ss;
  __syncthreads();
  float tot = red[0] + red[1] + red[2] + red[3];
  float scale = rsqrtf(tot * (1.0f / DMODEL) + 1e-6f);
  const float4 wv = *(const float4*)(w + tid * 4);
  float4 o;
  o.x = v.x * scale * wv.x;
  o.y = v.y * scale * wv.y;
  o.z = v.z * scale * wv.z;
  o.w = v.w * scale * wv.w;
  *(float4*)(xn + (size_t)row * DMODEL + tid * 4) = o;
}

// Generic f32 tiled GEMM: C[M,N] = A[M,K] @ B[K,N], both row-major.
// 64x64 tile, BK=16, 256 threads, 4x4 per thread. mode 1: softplus(acc + bias[col]).
__global__ __launch_bounds__(256) void gemm_f32(const float* __restrict__ A,
                                                const float* __restrict__ B,
                                                float* __restrict__ C, int M, int N, int K,
                                                int mode, const float* __restrict__ bias) {
  __shared__ __align__(16) float As[16][68];  // [k][m], pad 68 (68*4B = 17*16B, keeps 16B align)
  __shared__ __align__(16) float Bs[16][68];  // [k][n]
  const int tid = threadIdx.x;
  const int bm = blockIdx.y * 64;
  const int bn = blockIdx.x * 64;
  const int ty = tid >> 4, tx = tid & 15;
  const int lr = tid >> 2, lc = (tid & 3) << 2;   // A tile loader: row 0..63, k 0/4/8/12
  const int br = tid >> 4, bc = (tid & 15) << 2;  // B tile loader: k 0..15, col*4
  float acc[4][4] = {};
  for (int k0 = 0; k0 < K; k0 += 16) {
    float4 av = *(const float4*)(A + (size_t)(bm + lr) * K + k0 + lc);
    As[lc + 0][lr] = av.x;
    As[lc + 1][lr] = av.y;
    As[lc + 2][lr] = av.z;
    As[lc + 3][lr] = av.w;
    float4 bv = *(const float4*)(B + (size_t)(k0 + br) * N + bn + bc);
    *(float4*)&Bs[br][bc] = bv;
    __syncthreads();
#pragma unroll
    for (int kk = 0; kk < 16; ++kk) {
      float4 a4 = *(const float4*)&As[kk][ty << 2];
      float4 b4 = *(const float4*)&Bs[kk][tx << 2];
      float a[4] = {a4.x, a4.y, a4.z, a4.w};
      float b[4] = {b4.x, b4.y, b4.z, b4.w};
#pragma unroll
      for (int i = 0; i < 4; ++i)
#pragma unroll
        for (int j = 0; j < 4; ++j) acc[i][j] = fmaf(a[i], b[j], acc[i][j]);
    }
    __syncthreads();
  }
#pragma unroll
  for (int i = 0; i < 4; ++i) {
    int r = bm + (ty << 2) + i;
#pragma unroll
    for (int j = 0; j < 4; ++j) {
      int c = bn + (tx << 2) + j;
      float v = acc[i][j];
      if (mode == 1) v = softplus_f(v + bias[c]);
      C[(size_t)r * N + c] = v;
    }
  }
}

// x_inner = xg[:, :DINNER] * silu(xg[:, DINNER:])
__global__ __launch_bounds__(256) void gate_silu_k(const float* __restrict__ xg,
                                                   float* __restrict__ xi) {
  int idx = blockIdx.x * 256 + threadIdx.x;  // over NTOK * (DINNER/4)
  int row = idx >> 9;                        // DINNER/4 = 512
  int c4 = (idx & 511) << 2;
  float4 a = *(const float4*)(xg + (size_t)row * (2 * DINNER) + c4);
  float4 g = *(const float4*)(xg + (size_t)row * (2 * DINNER) + DINNER + c4);
  float4 o;
  o.x = a.x * (g.x / (1.f + __expf(-g.x)));
  o.y = a.y * (g.y / (1.f + __expf(-g.y)));
  o.z = a.z * (g.z / (1.f + __expf(-g.z)));
  o.w = a.w * (g.w / (1.f + __expf(-g.w)));
  *(float4*)(xi + (size_t)row * DINNER + c4) = o;
}

// causal depthwise conv, width 4, left pad 3.
__global__ __launch_bounds__(256) void dwconv_k(const float* __restrict__ xi,
                                                const float* __restrict__ w,
                                                float* __restrict__ xc) {
  int idx = blockIdx.x * 256 + threadIdx.x;  // over BATCH*SEQ*(DINNER/4)
  int d4 = (idx & 511) << 2;
  int t = (idx >> 9) & (SEQ - 1);
  int b = idx >> 19;  // / (512*1024)
  float4 w0 = *(const float4*)(w + (d4 + 0) * 4);
  float4 w1 = *(const float4*)(w + (d4 + 1) * 4);
  float4 w2 = *(const float4*)(w + (d4 + 2) * 4);
  float4 w3 = *(const float4*)(w + (d4 + 3) * 4);
  const float wj0[4] = {w0.x, w0.y, w0.z, w0.w};
  const float wj1[4] = {w1.x, w1.y, w1.z, w1.w};
  const float wj2[4] = {w2.x, w2.y, w2.z, w2.w};
  const float wj3[4] = {w3.x, w3.y, w3.z, w3.w};
  float4 acc = {0.f, 0.f, 0.f, 0.f};
#pragma unroll
  for (int j = 0; j < 4; ++j) {
    int tt = t - 3 + j;
    if (tt < 0) continue;
    float4 xv = *(const float4*)(xi + ((size_t)(b * SEQ + tt)) * DINNER + d4);
    acc.x = fmaf(xv.x, wj0[j], acc.x);
    acc.y = fmaf(xv.y, wj1[j], acc.y);
    acc.z = fmaf(xv.z, wj2[j], acc.z);
    acc.w = fmaf(xv.w, wj3[j], acc.w);
  }
  *(float4*)(xc + ((size_t)(b * SEQ + t)) * DINNER + d4) = acc;
}

// Bm = xc @ B_w, Cm = xc @ C_w  (N=16 each). Block = 8 rows x 32 cols.
__global__ __launch_bounds__(256) void bc_proj_k(const float* __restrict__ xc,
                                                 const float* __restrict__ Bw,
                                                 const float* __restrict__ Cw,
                                                 float* __restrict__ Bm, float* __restrict__ Cm) {
  int row = blockIdx.x * 8 + (threadIdx.x >> 5);
  int col = threadIdx.x & 31;
  const float* w = (col < 16) ? Bw : Cw;
  int s = col & 15;
  const float* xr = xc + (size_t)row * DINNER;
  float acc = 0.f;
  for (int k = 0; k < DINNER; k += 4) {
    float4 xv = *(const float4*)(xr + k);
    acc = fmaf(xv.x, w[(k + 0) * DSTATE + s], acc);
    acc = fmaf(xv.y, w[(k + 1) * DSTATE + s], acc);
    acc = fmaf(xv.z, w[(k + 2) * DSTATE + s], acc);
    acc = fmaf(xv.w, w[(k + 3) * DSTATE + s], acc);
  }
  if (col < 16) Bm[(size_t)row * DSTATE + s] = acc;
  else          Cm[(size_t)row * DSTATE + s] = acc;
}

// K1: per-chunk local scan (h0 = 0). Stores final h and chunk decay P = exp(A * sum(dt)).
__global__ __launch_bounds__(256) void scan_local_k(const float* __restrict__ dt,
                                                    const float* __restrict__ xc,
                                                    const float* __restrict__ Bm,
                                                    const float* __restrict__ A,
                                                    float* __restrict__ hfin,
                                                    float* __restrict__ P) {
  int d = blockIdx.x * 256 + threadIdx.x;
  int c = blockIdx.y, b = blockIdx.z;
  float a[DSTATE], h[DSTATE];
#pragma unroll
  for (int s = 0; s < DSTATE; ++s) { a[s] = A[(size_t)d * DSTATE + s]; h[s] = 0.f; }
  float sdt = 0.f;
  int t0 = c * CLEN;
  for (int t = t0; t < t0 + CLEN; ++t) {
    size_t ro = (size_t)(b * SEQ + t);
    float dtv = dt[ro * DINNER + d];
    float xv = xc[ro * DINNER + d];
    sdt += dtv;
    float bx = dtv * xv;
    float4 q0 = *(const float4*)(Bm + ro * DSTATE + 0);
    float4 q1 = *(const float4*)(Bm + ro * DSTATE + 4);
    float4 q2 = *(const float4*)(Bm + ro * DSTATE + 8);
    float4 q3 = *(const float4*)(Bm + ro * DSTATE + 12);
    float bm[DSTATE] = {q0.x, q0.y, q0.z, q0.w, q1.x, q1.y, q1.z, q1.w,
                        q2.x, q2.y, q2.z, q2.w, q3.x, q3.y, q3.z, q3.w};
#pragma unroll
    for (int s = 0; s < DSTATE; ++s) {
      float av = __expf(a[s] * dtv);
      h[s] = fmaf(av, h[s], bx * bm[s]);
    }
  }
  size_t o = ((size_t)(b * NCHUNK + c) * DINNER + d) * DSTATE;
#pragma unroll
  for (int s = 0; s < DSTATE; ++s) {
    hfin[o + s] = h[s];
    P[o + s] = __expf(a[s] * sdt);
  }
}

// K2: sequential scan over the 32 chunk states. Hprev[c] = state entering chunk c.
__global__ __launch_bounds__(256) void scan_chunks_k(const float* __restrict__ hfin,
                                                     const float* __restrict__ P,
                                                     float* __restrict__ Hprev) {
  int j = blockIdx.x * 256 + threadIdx.x;  // over BATCH*DINNER*DSTATE
  int b = j / (DINNER * DSTATE);
  int r = j % (DINNER * DSTATE);
  float H = 0.f;
  for (int c = 0; c < NCHUNK; ++c) {
    size_t o = ((size_t)(b * NCHUNK + c) * DINNER * DSTATE) + r;
    Hprev[o] = H;
    H = fmaf(P[o], H, hfin[o]);
  }
}

// K3: replay each chunk seeded with Hprev, emit y.
__global__ __launch_bounds__(256) void scan_final_k(const float* __restrict__ dt,
                                                    const float* __restrict__ xc,
                                                    const float* __restrict__ Bm,
                                                    const float* __restrict__ Cm,
                                                    const float* __restrict__ A,
                                                    const float* __restrict__ Hprev,
                                                    const float* __restrict__ Dskip,
                                                    float* __restrict__ ys) {
  int d = blockIdx.x * 256 + threadIdx.x;
  int c = blockIdx.y, b = blockIdx.z;
  float a[DSTATE], h[DSTATE];
  size_t ho = ((size_t)(b * NCHUNK + c) * DINNER + d) * DSTATE;
#pragma unroll
  for (int s = 0; s < DSTATE; ++s) {
    a[s] = A[(size_t)d * DSTATE + s];
    h[s] = Hprev[ho + s];
  }
  float Dv = Dskip[d];
  int t0 = c * CLEN;
  for (int t = t0; t < t0 + CLEN; ++t) {
    size_t ro = (size_t)(b * SEQ + t);
    float dtv = dt[ro * DINNER + d];
    float xv = xc[ro * DINNER + d];
    float bx = dtv * xv;
    float4 q0 = *(const float4*)(Bm + ro * DSTATE + 0);
    float4 q1 = *(const float4*)(Bm + ro * DSTATE + 4);
    float4 q2 = *(const float4*)(Bm + ro * DSTATE + 8);
    float4 q3 = *(const float4*)(Bm + ro * DSTATE + 12);
    float bm[DSTATE] = {q0.x, q0.y, q0.z, q0.w, q1.x, q1.y, q1.z, q1.w,
                        q2.x, q2.y, q2.z, q2.w, q3.x, q3.y, q3.z, q3.w};
    float4 r0 = *(const float4*)(Cm + ro * DSTATE + 0);
    float4 r1 = *(const float4*)(Cm + ro * DSTATE + 4);
    float4 r2 = *(const float4*)(Cm + ro * DSTATE + 8);
    float4 r3 = *(const float4*)(Cm + ro * DSTATE + 12);
    float cm[DSTATE] = {r0.x, r0.y, r0.z, r0.w, r1.x, r1.y, r1.z, r1.w,
                        r2.x, r2.y, r2.z, r2.w, r3.x, r3.y, r3.z, r3.w};
    float y = Dv * xv;
#pragma unroll
    for (int s = 0; s < DSTATE; ++s) {
      float av = __expf(a[s] * dtv);
      h[s] = fmaf(av, h[s], bx * bm[s]);
      y = fmaf(h[s], cm[s], y);
    }
    ys[ro * DINNER + d] = y;
  }
}

extern "C" void kernel_launch(void* const* d_in, const int* in_sizes, int n_in,
                              void* d_out, int out_size, void* d_ws, size_t ws_size,
                              hipStream_t stream) {
  (void)in_sizes; (void)n_in; (void)out_size; (void)ws_size;
  const float* x       = (const float*)d_in[0];
  const float* norm_w  = (const float*)d_in[1];
  const float* in_proj = (const float*)d_in[2];
  const float* conv_w  = (const float*)d_in[3];
  const float* dt_w    = (const float*)d_in[4];
  const float* dt_b    = (const float*)d_in[5];
  const float* A_log   = (const float*)d_in[6];
  const float* B_w     = (const float*)d_in[7];
  const float* C_w     = (const float*)d_in[8];
  const float* D_skip  = (const float*)d_in[9];
  const float* out_w   = (const float*)d_in[10];
  float* out = (float*)d_out;
  float* ws = (float*)d_ws;

  // Workspace layout (floats), with lifetime-safe aliasing:
  float* Aneg = ws;            // 32768
  float* Bm   = ws + 32768;    // 32768
  float* Cm   = ws + 65536;    // 32768
  float* xg   = ws + 131072;   // 8M region: later reused as dt(4M) + hfin(2M) + P(2M)
  float* dtb  = xg;            // 4M   (xg dead after gate_silu)
  float* hfin = xg + 4194304;  // 2M
  float* Pbuf = xg + 6291456;  // 2M
  float* xn   = ws + 131072 + 8388608;  // 2M, reused as Hprev (xn dead after in_proj GEMM)
  float* Hprev = xn;
  float* xinner = xn + 2097152;  // 4M, reused as ys (xinner dead after conv)
  float* ys     = xinner;
  float* xc   = xinner + 4194304;  // 4M (live through scan_final)

  init_aneg_k<<<dim3(DINNER * DSTATE / 256), dim3(256), 0, stream>>>(A_log, Aneg);
  rmsnorm_k<<<dim3(NTOK), dim3(256), 0, stream>>>(x, norm_w, xn);
  gemm_f32<<<dim3(2 * DINNER / 64, NTOK / 64), dim3(256), 0, stream>>>(
      xn, in_proj, xg, NTOK, 2 * DINNER, DMODEL, 0, nullptr);
  gate_silu_k<<<dim3(NTOK * (DINNER / 4) / 256), dim3(256), 0, stream>>>(xg, xinner);
  dwconv_k<<<dim3(NTOK * (DINNER / 4) / 256), dim3(256), 0, stream>>>(xinner, conv_w, xc);
  gemm_f32<<<dim3(DINNER / 64, NTOK / 64), dim3(256), 0, stream>>>(
      xc, dt_w, dtb, NTOK, DINNER, DINNER, 1, dt_b);
  bc_proj_k<<<dim3(NTOK / 8), dim3(256), 0, stream>>>(xc, B_w, C_w, Bm, Cm);
  scan_local_k<<<dim3(DINNER / 256, NCHUNK, BATCH), dim3(256), 0, stream>>>(
      dtb, xc, Bm, Aneg, hfin, Pbuf);
  scan_chunks_k<<<dim3(BATCH * DINNER * DSTATE / 256), dim3(256), 0, stream>>>(
      hfin, Pbuf, Hprev);
  scan_final_k<<<dim3(DINNER / 256, NCHUNK, BATCH), dim3(256), 0, stream>>>(
      dtb, xc, Bm, Cm, Aneg, Hprev, D_skip, ys);
  gemm_f32<<<dim3(DMODEL / 64, NTOK / 64), dim3(256), 0, stream>>>(
      ys, out_w, out, NTOK, DMODEL, DINNER, 0, nullptr);
}

// Round 2
// 291.486 us; speedup vs baseline: 2.5619x; 2.5619x over previous
//
#include <hip/hip_runtime.h>
#include <cmath>

// SSM forward, round 2: bf16-MFMA GEMMs (m97-style 128x128 tile, global_load_lds),
// on-device weight transpose+cvt, producers emit bf16 activation copies.

#define SEQ    1024
#define BATCH  2
#define DMODEL 1024
#define DINNER 2048
#define DSTATE 16
#define NTOK   (BATCH * SEQ)
#define NCHUNK 32
#define CLEN   32

typedef __attribute__((ext_vector_type(8))) short short8;
typedef __attribute__((ext_vector_type(4))) float f32x4;

__device__ __forceinline__ unsigned short f2bf(float f) {
  unsigned int u = __float_as_uint(f);
  unsigned int r = (u + 0x7fffu + ((u >> 16) & 1u)) >> 16;
  return (unsigned short)r;
}

__device__ __forceinline__ float softplus_f(float x) {
  return (x > 20.f) ? x : log1pf(__expf(x));
}

__device__ __forceinline__ void gload_lds16(const void* g, void* l) {
  __builtin_amdgcn_global_load_lds(
      (const __attribute__((address_space(1))) unsigned int*)g,
      (__attribute__((address_space(3))) unsigned int*)l, 16, 0, 0);
}

__global__ __launch_bounds__(256) void init_aneg_k(const float* __restrict__ A_log,
                                                   float* __restrict__ Aneg) {
  int i = blockIdx.x * 256 + threadIdx.x;
  Aneg[i] = -__expf(A_log[i]);
}

// W[K][N] f32 -> Wt[N][K] bf16, 32x32 LDS tiles.
__global__ void transpose_cvt_k(const float* __restrict__ W, unsigned short* __restrict__ Wt,
                                int K, int N) {
  __shared__ float tile[32][33];
  int k0 = blockIdx.y * 32, n0 = blockIdx.x * 32;
  int tx = threadIdx.x, ty = threadIdx.y;  // 32 x 8
#pragma unroll
  for (int i = 0; i < 32; i += 8)
    tile[ty + i][tx] = W[(size_t)(k0 + ty + i) * N + n0 + tx];
  __syncthreads();
#pragma unroll
  for (int i = 0; i < 32; i += 8)
    Wt[(size_t)(n0 + ty + i) * K + k0 + tx] = f2bf(tile[tx][ty + i]);
}

__global__ __launch_bounds__(256) void rmsnorm_k(const float* __restrict__ x,
                                                 const float* __restrict__ w,
                                                 unsigned short* __restrict__ xnbf) {
  int row = blockIdx.x, tid = threadIdx.x;
  const float4 v = *(const float4*)(x + (size_t)row * DMODEL + tid * 4);
  float ss = v.x * v.x + v.y * v.y + v.z * v.z + v.w * v.w;
#pragma unroll
  for (int off = 32; off > 0; off >>= 1) ss += __shfl_down(ss, off);
  __shared__ float red[4];
  if ((tid & 63) == 0) red[tid >> 6] = ss;
  __syncthreads();
  float tot = red[0] + red[1] + red[2] + red[3];
  float scale = rsqrtf(tot * (1.0f / DMODEL) + 1e-6f);
  const float4 wv = *(const float4*)(w + tid * 4);
  ushort4 o;
  o.x = f2bf(v.x * scale * wv.x);
  o.y = f2bf(v.y * scale * wv.y);
  o.z = f2bf(v.z * scale * wv.z);
  o.w = f2bf(v.w * scale * wv.w);
  *(ushort4*)(xnbf + (size_t)row * DMODEL + tid * 4) = o;
}

// C[M,N] = A[M,K](bf16,row-major) @ Bt[N,K](bf16)^T, f32 out.
// 128x128 tile, BK=32, 4 waves (2x2), 4x4 16x16x32 frags per wave.
// mode 1: C = softplus(acc + bias[col]).
__global__ __launch_bounds__(256) void gemm_bf16(const unsigned short* __restrict__ A,
                                                 const unsigned short* __restrict__ Bt,
                                                 float* __restrict__ C,
                                                 int M, int N, int K,
                                                 int mode, const float* __restrict__ bias) {
  __shared__ __align__(16) unsigned short Abuf[128 * 32];
  __shared__ __align__(16) unsigned short Bbuf[128 * 32];
  const int tid = threadIdx.x;
  const int wave = tid >> 6, lane = tid & 63;
  const int bm = blockIdx.y * 128, bn = blockIdx.x * 128;
  const int wm = wave >> 1, wn = wave & 1;
  const int lrow = lane & 15, lk = (lane >> 4) * 8;

  const int c0 = 2 * wave, c1 = c0 + 1;
  const int srow0 = 16 * c0 + (lane >> 2);
  const int srow1 = 16 * c1 + (lane >> 2);
  const int skoff = (lane & 3) * 8;
  const unsigned short* Ag0 = A + (size_t)(bm + srow0) * K + skoff;
  const unsigned short* Ag1 = A + (size_t)(bm + srow1) * K + skoff;
  const unsigned short* Bg0 = Bt + (size_t)(bn + srow0) * K + skoff;
  const unsigned short* Bg1 = Bt + (size_t)(bn + srow1) * K + skoff;

  f32x4 acc[4][4] = {};
  for (int k0 = 0; k0 < K; k0 += 32) {
    gload_lds16(Ag0 + k0, Abuf + c0 * 512);
    gload_lds16(Ag1 + k0, Abuf + c1 * 512);
    gload_lds16(Bg0 + k0, Bbuf + c0 * 512);
    gload_lds16(Bg1 + k0, Bbuf + c1 * 512);
    __syncthreads();
    short8 af[4], bfr[4];
#pragma unroll
    for (int m = 0; m < 4; ++m)
      af[m] = *(const short8*)&Abuf[(wm * 64 + m * 16 + lrow) * 32 + lk];
#pragma unroll
    for (int n = 0; n < 4; ++n)
      bfr[n] = *(const short8*)&Bbuf[(wn * 64 + n * 16 + lrow) * 32 + lk];
#pragma unroll
    for (int m = 0; m < 4; ++m)
#pragma unroll
      for (int n = 0; n < 4; ++n)
        acc[m][n] = __builtin_amdgcn_mfma_f32_16x16x32_bf16(af[m], bfr[n], acc[m][n], 0, 0, 0);
    __syncthreads();
  }

  const int rbase = bm + wm * 64 + (lane >> 4) * 4;
  const int cbase = bn + wn * 64 + lrow;
#pragma unroll
  for (int m = 0; m < 4; ++m)
#pragma unroll
    for (int n = 0; n < 4; ++n) {
      int col = cbase + n * 16;
      float bv = (mode == 1) ? bias[col] : 0.f;
#pragma unroll
      for (int r = 0; r < 4; ++r) {
        int row = rbase + m * 16 + r;
        float v = acc[m][n][r];
        if (mode == 1) v = softplus_f(v + bv);
        C[(size_t)row * N + col] = v;
      }
    }
}

__global__ __launch_bounds__(256) void gate_silu_k(const float* __restrict__ xg,
                                                   float* __restrict__ xi) {
  int idx = blockIdx.x * 256 + threadIdx.x;
  int row = idx >> 9;
  int c4 = (idx & 511) << 2;
  float4 a = *(const float4*)(xg + (size_t)row * (2 * DINNER) + c4);
  float4 g = *(const float4*)(xg + (size_t)row * (2 * DINNER) + DINNER + c4);
  float4 o;
  o.x = a.x * (g.x / (1.f + __expf(-g.x)));
  o.y = a.y * (g.y / (1.f + __expf(-g.y)));
  o.z = a.z * (g.z / (1.f + __expf(-g.z)));
  o.w = a.w * (g.w / (1.f + __expf(-g.w)));
  *(float4*)(xi + (size_t)row * DINNER + c4) = o;
}

// causal depthwise conv, width 4; writes f32 xc and bf16 xc copy.
__global__ __launch_bounds__(256) void dwconv_k(const float* __restrict__ xi,
                                                const float* __restrict__ w,
                                                float* __restrict__ xc,
                                                unsigned short* __restrict__ xcbf) {
  int idx = blockIdx.x * 256 + threadIdx.x;
  int d4 = (idx & 511) << 2;
  int t = (idx >> 9) & (SEQ - 1);
  int b = idx >> 19;
  float4 w0 = *(const float4*)(w + (d4 + 0) * 4);
  float4 w1 = *(const float4*)(w + (d4 + 1) * 4);
  float4 w2 = *(const float4*)(w + (d4 + 2) * 4);
  float4 w3 = *(const float4*)(w + (d4 + 3) * 4);
  const float wj0[4] = {w0.x, w0.y, w0.z, w0.w};
  const float wj1[4] = {w1.x, w1.y, w1.z, w1.w};
  const float wj2[4] = {w2.x, w2.y, w2.z, w2.w};
  const float wj3[4] = {w3.x, w3.y, w3.z, w3.w};
  float4 acc = {0.f, 0.f, 0.f, 0.f};
#pragma unroll
  for (int j = 0; j < 4; ++j) {
    int tt = t - 3 + j;
    if (tt < 0) continue;
    float4 xv = *(const float4*)(xi + ((size_t)(b * SEQ + tt)) * DINNER + d4);
    acc.x = fmaf(xv.x, wj0[j], acc.x);
    acc.y = fmaf(xv.y, wj1[j], acc.y);
    acc.z = fmaf(xv.z, wj2[j], acc.z);
    acc.w = fmaf(xv.w, wj3[j], acc.w);
  }
  size_t o = ((size_t)(b * SEQ + t)) * DINNER + d4;
  *(float4*)(xc + o) = acc;
  ushort4 ob = {f2bf(acc.x), f2bf(acc.y), f2bf(acc.z), f2bf(acc.w)};
  *(ushort4*)(xcbf + o) = ob;
}

__global__ __launch_bounds__(256) void bc_proj_k(const float* __restrict__ xc,
                                                 const float* __restrict__ Bw,
                                                 const float* __restrict__ Cw,
                                                 float* __restrict__ Bm, float* __restrict__ Cm) {
  int row = blockIdx.x * 8 + (threadIdx.x >> 5);
  int col = threadIdx.x & 31;
  const float* w = (col < 16) ? Bw : Cw;
  int s = col & 15;
  const float* xr = xc + (size_t)row * DINNER;
  float acc = 0.f;
  for (int k = 0; k < DINNER; k += 4) {
    float4 xv = *(const float4*)(xr + k);
    acc = fmaf(xv.x, w[(k + 0) * DSTATE + s], acc);
    acc = fmaf(xv.y, w[(k + 1) * DSTATE + s], acc);
    acc = fmaf(xv.z, w[(k + 2) * DSTATE + s], acc);
    acc = fmaf(xv.w, w[(k + 3) * DSTATE + s], acc);
  }
  if (col < 16) Bm[(size_t)row * DSTATE + s] = acc;
  else          Cm[(size_t)row * DSTATE + s] = acc;
}

__global__ __launch_bounds__(256) void scan_local_k(const float* __restrict__ dt,
                                                    const float* __restrict__ xc,
                                                    const float* __restrict__ Bm,
                                                    const float* __restrict__ A,
                                                    float* __restrict__ hfin,
                                                    float* __restrict__ P) {
  int d = blockIdx.x * 256 + threadIdx.x;
  int c = blockIdx.y, b = blockIdx.z;
  float a[DSTATE], h[DSTATE];
#pragma unroll
  for (int s = 0; s < DSTATE; ++s) { a[s] = A[(size_t)d * DSTATE + s]; h[s] = 0.f; }
  float sdt = 0.f;
  int t0 = c * CLEN;
  for (int t = t0; t < t0 + CLEN; ++t) {
    size_t ro = (size_t)(b * SEQ + t);
    float dtv = dt[ro * DINNER + d];
    float xv = xc[ro * DINNER + d];
    sdt += dtv;
    float bx = dtv * xv;
    float4 q0 = *(const float4*)(Bm + ro * DSTATE + 0);
    float4 q1 = *(const float4*)(Bm + ro * DSTATE + 4);
    float4 q2 = *(const float4*)(Bm + ro * DSTATE + 8);
    float4 q3 = *(const float4*)(Bm + ro * DSTATE + 12);
    float bm[DSTATE] = {q0.x, q0.y, q0.z, q0.w, q1.x, q1.y, q1.z, q1.w,
                        q2.x, q2.y, q2.z, q2.w, q3.x, q3.y, q3.z, q3.w};
#pragma unroll
    for (int s = 0; s < DSTATE; ++s) {
      float av = __expf(a[s] * dtv);
      h[s] = fmaf(av, h[s], bx * bm[s]);
    }
  }
  size_t o = ((size_t)(b * NCHUNK + c) * DINNER + d) * DSTATE;
#pragma unroll
  for (int s = 0; s < DSTATE; ++s) {
    hfin[o + s] = h[s];
    P[o + s] = __expf(a[s] * sdt);
  }
}

__global__ __launch_bounds__(256) void scan_chunks_k(const float* __restrict__ hfin,
                                                     const float* __restrict__ P,
                                                     float* __restrict__ Hprev) {
  int j = blockIdx.x * 256 + threadIdx.x;
  int b = j / (DINNER * DSTATE);
  int r = j % (DINNER * DSTATE);
  float H = 0.f;
  for (int c = 0; c < NCHUNK; ++c) {
    size_t o = ((size_t)(b * NCHUNK + c) * DINNER * DSTATE) + r;
    Hprev[o] = H;
    H = fmaf(P[o], H, hfin[o]);
  }
}

__global__ __launch_bounds__(256) void scan_final_k(const float* __restrict__ dt,
                                                    const float* __restrict__ xc,
                                                    const float* __restrict__ Bm,
                                                    const float* __restrict__ Cm,
                                                    const float* __restrict__ A,
                                                    const float* __restrict__ Hprev,
                                                    const float* __restrict__ Dskip,
                                                    unsigned short* __restrict__ ysbf) {
  int d = blockIdx.x * 256 + threadIdx.x;
  int c = blockIdx.y, b = blockIdx.z;
  float a[DSTATE], h[DSTATE];
  size_t ho = ((size_t)(b * NCHUNK + c) * DINNER + d) * DSTATE;
#pragma unroll
  for (int s = 0; s < DSTATE; ++s) {
    a[s] = A[(size_t)d * DSTATE + s];
    h[s] = Hprev[ho + s];
  }
  float Dv = Dskip[d];
  int t0 = c * CLEN;
  for (int t = t0; t < t0 + CLEN; ++t) {
    size_t ro = (size_t)(b * SEQ + t);
    float dtv = dt[ro * DINNER + d];
    float xv = xc[ro * DINNER + d];
    float bx = dtv * xv;
    float4 q0 = *(const float4*)(Bm + ro * DSTATE + 0);
    float4 q1 = *(const float4*)(Bm + ro * DSTATE + 4);
    float4 q2 = *(const float4*)(Bm + ro * DSTATE + 8);
    float4 q3 = *(const float4*)(Bm + ro * DSTATE + 12);
    float bm[DSTATE] = {q0.x, q0.y, q0.z, q0.w, q1.x, q1.y, q1.z, q1.w,
                        q2.x, q2.y, q2.z, q2.w, q3.x, q3.y, q3.z, q3.w};
    float4 r0 = *(const float4*)(Cm + ro * DSTATE + 0);
    float4 r1 = *(const float4*)(Cm + ro * DSTATE + 4);
    float4 r2 = *(const float4*)(Cm + ro * DSTATE + 8);
    float4 r3 = *(const float4*)(Cm + ro * DSTATE + 12);
    float cm[DSTATE] = {r0.x, r0.y, r0.z, r0.w, r1.x, r1.y, r1.z, r1.w,
                        r2.x, r2.y, r2.z, r2.w, r3.x, r3.y, r3.z, r3.w};
    float y = Dv * xv;
#pragma unroll
    for (int s = 0; s < DSTATE; ++s) {
      float av = __expf(a[s] * dtv);
      h[s] = fmaf(av, h[s], bx * bm[s]);
      y = fmaf(h[s], cm[s], y);
    }
    ysbf[ro * DINNER + d] = f2bf(y);
  }
}

extern "C" void kernel_launch(void* const* d_in, const int* in_sizes, int n_in,
                              void* d_out, int out_size, void* d_ws, size_t ws_size,
                              hipStream_t stream) {
  (void)in_sizes; (void)n_in; (void)out_size; (void)ws_size;
  const float* x       = (const float*)d_in[0];
  const float* norm_w  = (const float*)d_in[1];
  const float* in_proj = (const float*)d_in[2];
  const float* conv_w  = (const float*)d_in[3];
  const float* dt_w    = (const float*)d_in[4];
  const float* dt_b    = (const float*)d_in[5];
  const float* A_log   = (const float*)d_in[6];
  const float* B_w     = (const float*)d_in[7];
  const float* C_w     = (const float*)d_in[8];
  const float* D_skip  = (const float*)d_in[9];
  const float* out_w   = (const float*)d_in[10];
  float* out = (float*)d_out;
  float* ws = (float*)d_ws;

  // Workspace (floats). Total = 98304 + 4M + 4M + 8M = 16,875,520 f32 (67.5 MB).
  float* Aneg = ws;                 // 32768, live all
  float* Bm   = ws + 32768;         // 32768
  float* Cm   = ws + 65536;         // 32768
  float* R1   = ws + 98304;         // 4M f32
  float* R2   = R1 + 4194304;       // 4M f32
  float* R3   = R2 + 4194304;       // 8M f32
  // R1 timeline: [in_wT(2M f32) | xn_bf(1M f32)] -> xinner(4M) -> dtb(4M) -> out_wT(1M)
  unsigned short* in_wT  = (unsigned short*)R1;
  unsigned short* xn_bf  = (unsigned short*)(R1 + 2097152);
  float* xinner = R1;
  float* dtb    = R1;
  unsigned short* out_wT = (unsigned short*)R1;
  float* xc = R2;  // live dwconv -> scan_final
  // R3 timeline: xg(8M) -> [xc_bf(2M f32)|dt_wT(2M f32)|hfin(2M)|P(2M)] ; Hprev over dt_wT ; ys_bf over xc_bf
  float* xg = R3;
  unsigned short* xc_bf = (unsigned short*)R3;
  unsigned short* ys_bf = (unsigned short*)R3;
  unsigned short* dt_wT = (unsigned short*)(R3 + 2097152);
  float* Hprev = R3 + 2097152;
  float* hfin  = R3 + 4194304;
  float* Pbuf  = R3 + 6291456;

  init_aneg_k<<<dim3(DINNER * DSTATE / 256), dim3(256), 0, stream>>>(A_log, Aneg);
  transpose_cvt_k<<<dim3(2 * DINNER / 32, DMODEL / 32), dim3(32, 8), 0, stream>>>(
      in_proj, in_wT, DMODEL, 2 * DINNER);
  rmsnorm_k<<<dim3(NTOK), dim3(256), 0, stream>>>(x, norm_w, xn_bf);
  gemm_bf16<<<dim3(2 * DINNER / 128, NTOK / 128), dim3(256), 0, stream>>>(
      xn_bf, in_wT, xg, NTOK, 2 * DINNER, DMODEL, 0, nullptr);
  gate_silu_k<<<dim3(NTOK * (DINNER / 4) / 256), dim3(256), 0, stream>>>(xg, xinner);
  dwconv_k<<<dim3(NTOK * (DINNER / 4) / 256), dim3(256), 0, stream>>>(xinner, conv_w, xc, xc_bf);
  transpose_cvt_k<<<dim3(DINNER / 32, DINNER / 32), dim3(32, 8), 0, stream>>>(
      dt_w, dt_wT, DINNER, DINNER);
  gemm_bf16<<<dim3(DINNER / 128, NTOK / 128), dim3(256), 0, stream>>>(
      xc_bf, dt_wT, dtb, NTOK, DINNER, DINNER, 1, dt_b);
  bc_proj_k<<<dim3(NTOK / 8), dim3(256), 0, stream>>>(xc, B_w, C_w, Bm, Cm);
  scan_local_k<<<dim3(DINNER / 256, NCHUNK, BATCH), dim3(256), 0, stream>>>(
      dtb, xc, Bm, Aneg, hfin, Pbuf);
  scan_chunks_k<<<dim3(BATCH * DINNER * DSTATE / 256), dim3(256), 0, stream>>>(
      hfin, Pbuf, Hprev);
  scan_final_k<<<dim3(DINNER / 256, NCHUNK, BATCH), dim3(256), 0, stream>>>(
      dtb, xc, Bm, Cm, Aneg, Hprev, D_skip, ys_bf);
  transpose_cvt_k<<<dim3(DMODEL / 32, DINNER / 32), dim3(32, 8), 0, stream>>>(
      out_w, out_wT, DINNER, DMODEL);
  gemm_bf16<<<dim3(DMODEL / 128, NTOK / 128), dim3(256), 0, stream>>>(
      ys_bf, out_wT, out, NTOK, DMODEL, DINNER, 0, nullptr);
}

// Round 3
// 240.397 us; speedup vs baseline: 3.1063x; 1.2125x over previous
//
#include <hip/hip_runtime.h>
#include <cmath>

// SSM forward, round 3: shape-tuned bf16 GEMM tiles (>=2 blocks/CU for every GEMM),
// fused silu-gate + depthwise conv.

#define SEQ    1024
#define BATCH  2
#define DMODEL 1024
#define DINNER 2048
#define DSTATE 16
#define NTOK   (BATCH * SEQ)
#define NCHUNK 32
#define CLEN   32

typedef __attribute__((ext_vector_type(8))) short short8;
typedef __attribute__((ext_vector_type(4))) float f32x4;

__device__ __forceinline__ unsigned short f2bf(float f) {
  unsigned int u = __float_as_uint(f);
  unsigned int r = (u + 0x7fffu + ((u >> 16) & 1u)) >> 16;
  return (unsigned short)r;
}

__device__ __forceinline__ float softplus_f(float x) {
  return (x > 20.f) ? x : log1pf(__expf(x));
}

__device__ __forceinline__ void gload_lds16(const void* g, void* l) {
  __builtin_amdgcn_global_load_lds(
      (const __attribute__((address_space(1))) unsigned int*)g,
      (__attribute__((address_space(3))) unsigned int*)l, 16, 0, 0);
}

__global__ __launch_bounds__(256) void init_aneg_k(const float* __restrict__ A_log,
                                                   float* __restrict__ Aneg) {
  int i = blockIdx.x * 256 + threadIdx.x;
  Aneg[i] = -__expf(A_log[i]);
}

// W[K][N] f32 -> Wt[N][K] bf16, 32x32 LDS tiles.
__global__ void transpose_cvt_k(const float* __restrict__ W, unsigned short* __restrict__ Wt,
                                int K, int N) {
  __shared__ float tile[32][33];
  int k0 = blockIdx.y * 32, n0 = blockIdx.x * 32;
  int tx = threadIdx.x, ty = threadIdx.y;  // 32 x 8
#pragma unroll
  for (int i = 0; i < 32; i += 8)
    tile[ty + i][tx] = W[(size_t)(k0 + ty + i) * N + n0 + tx];
  __syncthreads();
#pragma unroll
  for (int i = 0; i < 32; i += 8)
    Wt[(size_t)(n0 + ty + i) * K + k0 + tx] = f2bf(tile[tx][ty + i]);
}

__global__ __launch_bounds__(256) void rmsnorm_k(const float* __restrict__ x,
                                                 const float* __restrict__ w,
                                                 unsigned short* __restrict__ xnbf) {
  int row = blockIdx.x, tid = threadIdx.x;
  const float4 v = *(const float4*)(x + (size_t)row * DMODEL + tid * 4);
  float ss = v.x * v.x + v.y * v.y + v.z * v.z + v.w * v.w;
#pragma unroll
  for (int off = 32; off > 0; off >>= 1) ss += __shfl_down(ss, off);
  __shared__ float red[4];
  if ((tid & 63) == 0) red[tid >> 6] = ss;
  __syncthreads();
  float tot = red[0] + red[1] + red[2] + red[3];
  float scale = rsqrtf(tot * (1.0f / DMODEL) + 1e-6f);
  const float4 wv = *(const float4*)(w + tid * 4);
  ushort4 o;
  o.x = f2bf(v.x * scale * wv.x);
  o.y = f2bf(v.y * scale * wv.y);
  o.z = f2bf(v.z * scale * wv.z);
  o.w = f2bf(v.w * scale * wv.w);
  *(ushort4*)(xnbf + (size_t)row * DMODEL + tid * 4) = o;
}

// C[M,N] = A[M,K](bf16,row-major) @ Bt[N,K](bf16)^T, f32 out.
// BMxBN tile, BK=32, 4 waves (2x2), each wave (BM/2)x(BN/2).
// MODE 1: C = softplus(acc + bias[col]).
template <int BM, int BN, int MODE>
__global__ __launch_bounds__(256) void gemm_bf16_t(const unsigned short* __restrict__ A,
                                                   const unsigned short* __restrict__ Bt,
                                                   float* __restrict__ C,
                                                   int M, int N, int K,
                                                   const float* __restrict__ bias) {
  constexpr int WTM = BM / 2, WTN = BN / 2;
  constexpr int FM = WTM / 16, FN = WTN / 16;
  __shared__ __align__(16) unsigned short Abuf[BM * 32];
  __shared__ __align__(16) unsigned short Bbuf[BN * 32];
  const int tid = threadIdx.x;
  const int wave = tid >> 6, lane = tid & 63;
  const int bm = blockIdx.y * BM, bn = blockIdx.x * BN;
  const int wm = wave >> 1, wn = wave & 1;
  const int lrow = lane & 15, lk = (lane >> 4) * 8;
  const int srow = lane >> 2, skoff = (lane & 3) * 8;

  const unsigned short* Ag = A + (size_t)(bm + wave * 16 + srow) * K + skoff;
  const unsigned short* Bg = Bt + (size_t)(bn + wave * 16 + srow) * K + skoff;

  f32x4 acc[FM][FN] = {};
  for (int k0 = 0; k0 < K; k0 += 32) {
#pragma unroll
    for (int r = 0; r < BM / 64; ++r)
      gload_lds16(Ag + (size_t)r * 64 * K + k0, Abuf + (r * 64 + wave * 16) * 32);
#pragma unroll
    for (int r = 0; r < BN / 64; ++r)
      gload_lds16(Bg + (size_t)r * 64 * K + k0, Bbuf + (r * 64 + wave * 16) * 32);
    __syncthreads();
    short8 af[FM], bfr[FN];
#pragma unroll
    for (int m = 0; m < FM; ++m)
      af[m] = *(const short8*)&Abuf[(wm * WTM + m * 16 + lrow) * 32 + lk];
#pragma unroll
    for (int n = 0; n < FN; ++n)
      bfr[n] = *(const short8*)&Bbuf[(wn * WTN + n * 16 + lrow) * 32 + lk];
#pragma unroll
    for (int m = 0; m < FM; ++m)
#pragma unroll
      for (int n = 0; n < FN; ++n)
        acc[m][n] = __builtin_amdgcn_mfma_f32_16x16x32_bf16(af[m], bfr[n], acc[m][n], 0, 0, 0);
    __syncthreads();
  }

  const int rbase = bm + wm * WTM + (lane >> 4) * 4;
  const int cbase = bn + wn * WTN + lrow;
#pragma unroll
  for (int m = 0; m < FM; ++m)
#pragma unroll
    for (int n = 0; n < FN; ++n) {
      int col = cbase + n * 16;
      float bv = (MODE == 1) ? bias[col] : 0.f;
#pragma unroll
      for (int r = 0; r < 4; ++r) {
        int row = rbase + m * 16 + r;
        float v = acc[m][n][r];
        if (MODE == 1) v = softplus_f(v + bv);
        C[(size_t)row * N + col] = v;
      }
    }
}

// Fused: x_inner = a * silu(g) (from xg) then causal depthwise conv width 4.
// Thread: one d4 group, 8 consecutive t. Rolling window of gated values.
__global__ __launch_bounds__(256) void siluconv_k(const float* __restrict__ xg,
                                                  const float* __restrict__ w,
                                                  float* __restrict__ xc,
                                                  unsigned short* __restrict__ xcbf) {
  int idx = blockIdx.x * 256 + threadIdx.x;  // 131072 threads
  int d4 = (idx & 511) << 2;
  int tc = (idx >> 9) & 127;
  int b = idx >> 16;
  float4 w0 = *(const float4*)(w + (d4 + 0) * 4);
  float4 w1 = *(const float4*)(w + (d4 + 1) * 4);
  float4 w2 = *(const float4*)(w + (d4 + 2) * 4);
  float4 w3 = *(const float4*)(w + (d4 + 3) * 4);
  const float wj0[4] = {w0.x, w0.y, w0.z, w0.w};
  const float wj1[4] = {w1.x, w1.y, w1.z, w1.w};
  const float wj2[4] = {w2.x, w2.y, w2.z, w2.w};
  const float wj3[4] = {w3.x, w3.y, w3.z, w3.w};
  const float* pa = xg + (size_t)b * SEQ * (2 * DINNER) + d4;
  const float* pg = pa + DINNER;
  int t0 = tc * 8;
  float4 sA = {0.f, 0.f, 0.f, 0.f}, sB = sA, sC = sA;
  auto gated = [&](int t) {
    float4 a = *(const float4*)(pa + (size_t)t * (2 * DINNER));
    float4 g = *(const float4*)(pg + (size_t)t * (2 * DINNER));
    float4 r;
    r.x = a.x * (g.x / (1.f + __expf(-g.x)));
    r.y = a.y * (g.y / (1.f + __expf(-g.y)));
    r.z = a.z * (g.z / (1.f + __expf(-g.z)));
    r.w = a.w * (g.w / (1.f + __expf(-g.w)));
    return r;
  };
  if (t0 > 0) {
    sA = gated(t0 - 3);
    sB = gated(t0 - 2);
    sC = gated(t0 - 1);
  }
#pragma unroll
  for (int j = 0; j < 8; ++j) {
    int t = t0 + j;
    float4 sD = gated(t);
    float4 o;
    o.x = sA.x * wj0[0] + sB.x * wj0[1] + sC.x * wj0[2] + sD.x * wj0[3];
    o.y = sA.y * wj1[0] + sB.y * wj1[1] + sC.y * wj1[2] + sD.y * wj1[3];
    o.z = sA.z * wj2[0] + sB.z * wj2[1] + sC.z * wj2[2] + sD.z * wj2[3];
    o.w = sA.w * wj3[0] + sB.w * wj3[1] + sC.w * wj3[2] + sD.w * wj3[3];
    size_t ro = ((size_t)(b * SEQ + t)) * DINNER + d4;
    *(float4*)(xc + ro) = o;
    ushort4 ob = {f2bf(o.x), f2bf(o.y), f2bf(o.z), f2bf(o.w)};
    *(ushort4*)(xcbf + ro) = ob;
    sA = sB; sB = sC; sC = sD;
  }
}

__global__ __launch_bounds__(256) void bc_proj_k(const float* __restrict__ xc,
                                                 const float* __restrict__ Bw,
                                                 const float* __restrict__ Cw,
                                                 float* __restrict__ Bm, float* __restrict__ Cm) {
  int row = blockIdx.x * 8 + (threadIdx.x >> 5);
  int col = threadIdx.x & 31;
  const float* w = (col < 16) ? Bw : Cw;
  int s = col & 15;
  const float* xr = xc + (size_t)row * DINNER;
  float acc = 0.f;
  for (int k = 0; k < DINNER; k += 4) {
    float4 xv = *(const float4*)(xr + k);
    acc = fmaf(xv.x, w[(k + 0) * DSTATE + s], acc);
    acc = fmaf(xv.y, w[(k + 1) * DSTATE + s], acc);
    acc = fmaf(xv.z, w[(k + 2) * DSTATE + s], acc);
    acc = fmaf(xv.w, w[(k + 3) * DSTATE + s], acc);
  }
  if (col < 16) Bm[(size_t)row * DSTATE + s] = acc;
  else          Cm[(size_t)row * DSTATE + s] = acc;
}

__global__ __launch_bounds__(256) void scan_local_k(const float* __restrict__ dt,
                                                    const float* __restrict__ xc,
                                                    const float* __restrict__ Bm,
                                                    const float* __restrict__ A,
                                                    float* __restrict__ hfin,
                                                    float* __restrict__ P) {
  int d = blockIdx.x * 256 + threadIdx.x;
  int c = blockIdx.y, b = blockIdx.z;
  float a[DSTATE], h[DSTATE];
#pragma unroll
  for (int s = 0; s < DSTATE; ++s) { a[s] = A[(size_t)d * DSTATE + s]; h[s] = 0.f; }
  float sdt = 0.f;
  int t0 = c * CLEN;
  for (int t = t0; t < t0 + CLEN; ++t) {
    size_t ro = (size_t)(b * SEQ + t);
    float dtv = dt[ro * DINNER + d];
    float xv = xc[ro * DINNER + d];
    sdt += dtv;
    float bx = dtv * xv;
    float4 q0 = *(const float4*)(Bm + ro * DSTATE + 0);
    float4 q1 = *(const float4*)(Bm + ro * DSTATE + 4);
    float4 q2 = *(const float4*)(Bm + ro * DSTATE + 8);
    float4 q3 = *(const float4*)(Bm + ro * DSTATE + 12);
    float bm[DSTATE] = {q0.x, q0.y, q0.z, q0.w, q1.x, q1.y, q1.z, q1.w,
                        q2.x, q2.y, q2.z, q2.w, q3.x, q3.y, q3.z, q3.w};
#pragma unroll
    for (int s = 0; s < DSTATE; ++s) {
      float av = __expf(a[s] * dtv);
      h[s] = fmaf(av, h[s], bx * bm[s]);
    }
  }
  size_t o = ((size_t)(b * NCHUNK + c) * DINNER + d) * DSTATE;
#pragma unroll
  for (int s = 0; s < DSTATE; ++s) {
    hfin[o + s] = h[s];
    P[o + s] = __expf(a[s] * sdt);
  }
}

__global__ __launch_bounds__(256) void scan_chunks_k(const float* __restrict__ hfin,
                                                     const float* __restrict__ P,
                                                     float* __restrict__ Hprev) {
  int j = blockIdx.x * 256 + threadIdx.x;
  int b = j / (DINNER * DSTATE);
  int r = j % (DINNER * DSTATE);
  float H = 0.f;
  for (int c = 0; c < NCHUNK; ++c) {
    size_t o = ((size_t)(b * NCHUNK + c) * DINNER * DSTATE) + r;
    Hprev[o] = H;
    H = fmaf(P[o], H, hfin[o]);
  }
}

__global__ __launch_bounds__(256) void scan_final_k(const float* __restrict__ dt,
                                                    const float* __restrict__ xc,
                                                    const float* __restrict__ Bm,
                                                    const float* __restrict__ Cm,
                                                    const float* __restrict__ A,
                                                    const float* __restrict__ Hprev,
                                                    const float* __restrict__ Dskip,
                                                    unsigned short* __restrict__ ysbf) {
  int d = blockIdx.x * 256 + threadIdx.x;
  int c = blockIdx.y, b = blockIdx.z;
  float a[DSTATE], h[DSTATE];
  size_t ho = ((size_t)(b * NCHUNK + c) * DINNER + d) * DSTATE;
#pragma unroll
  for (int s = 0; s < DSTATE; ++s) {
    a[s] = A[(size_t)d * DSTATE + s];
    h[s] = Hprev[ho + s];
  }
  float Dv = Dskip[d];
  int t0 = c * CLEN;
  for (int t = t0; t < t0 + CLEN; ++t) {
    size_t ro = (size_t)(b * SEQ + t);
    float dtv = dt[ro * DINNER + d];
    float xv = xc[ro * DINNER + d];
    float bx = dtv * xv;
    float4 q0 = *(const float4*)(Bm + ro * DSTATE + 0);
    float4 q1 = *(const float4*)(Bm + ro * DSTATE + 4);
    float4 q2 = *(const float4*)(Bm + ro * DSTATE + 8);
    float4 q3 = *(const float4*)(Bm + ro * DSTATE + 12);
    float bm[DSTATE] = {q0.x, q0.y, q0.z, q0.w, q1.x, q1.y, q1.z, q1.w,
                        q2.x, q2.y, q2.z, q2.w, q3.x, q3.y, q3.z, q3.w};
    float4 r0 = *(const float4*)(Cm + ro * DSTATE + 0);
    float4 r1 = *(const float4*)(Cm + ro * DSTATE + 4);
    float4 r2 = *(const float4*)(Cm + ro * DSTATE + 8);
    float4 r3 = *(const float4*)(Cm + ro * DSTATE + 12);
    float cm[DSTATE] = {r0.x, r0.y, r0.z, r0.w, r1.x, r1.y, r1.z, r1.w,
                        r2.x, r2.y, r2.z, r2.w, r3.x, r3.y, r3.z, r3.w};
    float y = Dv * xv;
#pragma unroll
    for (int s = 0; s < DSTATE; ++s) {
      float av = __expf(a[s] * dtv);
      h[s] = fmaf(av, h[s], bx * bm[s]);
      y = fmaf(h[s], cm[s], y);
    }
    ysbf[ro * DINNER + d] = f2bf(y);
  }
}

extern "C" void kernel_launch(void* const* d_in, const int* in_sizes, int n_in,
                              void* d_out, int out_size, void* d_ws, size_t ws_size,
                              hipStream_t stream) {
  (void)in_sizes; (void)n_in; (void)out_size; (void)ws_size;
  const float* x       = (const float*)d_in[0];
  const float* norm_w  = (const float*)d_in[1];
  const float* in_proj = (const float*)d_in[2];
  const float* conv_w  = (const float*)d_in[3];
  const float* dt_w    = (const float*)d_in[4];
  const float* dt_b    = (const float*)d_in[5];
  const float* A_log   = (const float*)d_in[6];
  const float* B_w     = (const float*)d_in[7];
  const float* C_w     = (const float*)d_in[8];
  const float* D_skip  = (const float*)d_in[9];
  const float* out_w   = (const float*)d_in[10];
  float* out = (float*)d_out;
  float* ws = (float*)d_ws;

  // Workspace (f32 units), ~71.7 MB total, lifetime-aliased:
  float* Aneg = ws;                  // 32768
  float* Bm   = ws + 32768;
  float* Cm   = ws + 65536;
  float* RA   = ws + 98304;          // 2.097M f32: in_wT -> dt_wT -> Hprev
  float* RB   = RA + 2097152;        // 1.049M f32: xn_bf -> out_wT
  float* RC   = RB + 1048576;        // 8.389M f32: xg -> dtb(4M)+hfin(2.1M)+P(2.1M)
  float* RD   = RC + 8388608;        // 4.194M f32: xc
  float* RE   = RD + 4194304;        // 2.097M f32: xc_bf -> ys_bf
  unsigned short* in_wT  = (unsigned short*)RA;
  unsigned short* dt_wT  = (unsigned short*)RA;
  float*          Hprev  = RA;
  unsigned short* xn_bf  = (unsigned short*)RB;
  unsigned short* out_wT = (unsigned short*)RB;
  float* xg   = RC;
  float* dtb  = RC;
  float* hfin = RC + 4194304;
  float* Pbuf = RC + 6291456;
  float* xc   = RD;
  unsigned short* xc_bf = (unsigned short*)RE;
  unsigned short* ys_bf = (unsigned short*)RE;

  init_aneg_k<<<dim3(DINNER * DSTATE / 256), dim3(256), 0, stream>>>(A_log, Aneg);
  transpose_cvt_k<<<dim3(2 * DINNER / 32, DMODEL / 32), dim3(32, 8), 0, stream>>>(
      in_proj, in_wT, DMODEL, 2 * DINNER);
  rmsnorm_k<<<dim3(NTOK), dim3(256), 0, stream>>>(x, norm_w, xn_bf);
  gemm_bf16_t<128, 128, 0><<<dim3(2 * DINNER / 128, NTOK / 128), dim3(256), 0, stream>>>(
      xn_bf, in_wT, xg, NTOK, 2 * DINNER, DMODEL, nullptr);
  siluconv_k<<<dim3(NTOK * (DINNER / 4) / 8 / 256), dim3(256), 0, stream>>>(
      xg, conv_w, xc, xc_bf);
  transpose_cvt_k<<<dim3(DINNER / 32, DINNER / 32), dim3(32, 8), 0, stream>>>(
      dt_w, dt_wT, DINNER, DINNER);
  gemm_bf16_t<128, 64, 1><<<dim3(DINNER / 64, NTOK / 128), dim3(256), 0, stream>>>(
      xc_bf, dt_wT, dtb, NTOK, DINNER, DINNER, dt_b);
  bc_proj_k<<<dim3(NTOK / 8), dim3(256), 0, stream>>>(xc, B_w, C_w, Bm, Cm);
  scan_local_k<<<dim3(DINNER / 256, NCHUNK, BATCH), dim3(256), 0, stream>>>(
      dtb, xc, Bm, Aneg, hfin, Pbuf);
  scan_chunks_k<<<dim3(BATCH * DINNER * DSTATE / 256), dim3(256), 0, stream>>>(
      hfin, Pbuf, Hprev);
  scan_final_k<<<dim3(DINNER / 256, NCHUNK, BATCH), dim3(256), 0, stream>>>(
      dtb, xc, Bm, Cm, Aneg, Hprev, D_skip, ys_bf);
  transpose_cvt_k<<<dim3(DMODEL / 32, DINNER / 32), dim3(32, 8), 0, stream>>>(
      out_w, out_wT, DINNER, DMODEL);
  gemm_bf16_t<64, 64, 0><<<dim3(DMODEL / 64, NTOK / 64), dim3(256), 0, stream>>>(
      ys_bf, out_wT, out, NTOK, DMODEL, DINNER, nullptr);
}

// Round 4
// 201.291 us; speedup vs baseline: 3.7098x; 1.1943x over previous
//
#include <hip/hip_runtime.h>
#include <cmath>

// SSM forward, round 4: bc_proj folded into dt GEMM (combined 2112-col weight),
// 2-phase double-buffered GEMM (1 barrier/K-step), XCD-aware block swizzle.

#define SEQ    1024
#define BATCH  2
#define DMODEL 1024
#define DINNER 2048
#define DSTATE 16
#define NTOK   (BATCH * SEQ)
#define NCHUNK 32
#define CLEN   32
#define NEXT   2112  // DINNER + 16 + 16 + 32 pad (64-multiple)

typedef __attribute__((ext_vector_type(8))) short short8;
typedef __attribute__((ext_vector_type(4))) float f32x4;

__device__ __forceinline__ unsigned short f2bf(float f) {
  unsigned int u = __float_as_uint(f);
  unsigned int r = (u + 0x7fffu + ((u >> 16) & 1u)) >> 16;
  return (unsigned short)r;
}

__device__ __forceinline__ float softplus_f(float x) {
  return (x > 20.f) ? x : log1pf(__expf(x));
}

__device__ __forceinline__ void gload_lds16(const void* g, void* l) {
  __builtin_amdgcn_global_load_lds(
      (const __attribute__((address_space(1))) unsigned int*)g,
      (__attribute__((address_space(3))) unsigned int*)l, 16, 0, 0);
}

__global__ __launch_bounds__(256) void init_aneg_k(const float* __restrict__ A_log,
                                                   float* __restrict__ Aneg) {
  int i = blockIdx.x * 256 + threadIdx.x;
  Aneg[i] = -__expf(A_log[i]);
}

// W[K][N] f32 -> Wt[N][K] bf16, 32x32 LDS tiles.
__global__ void transpose_cvt_k(const float* __restrict__ W, unsigned short* __restrict__ Wt,
                                int K, int N) {
  __shared__ float tile[32][33];
  int k0 = blockIdx.y * 32, n0 = blockIdx.x * 32;
  int tx = threadIdx.x, ty = threadIdx.y;  // 32 x 8
#pragma unroll
  for (int i = 0; i < 32; i += 8)
    tile[ty + i][tx] = W[(size_t)(k0 + ty + i) * N + n0 + tx];
  __syncthreads();
#pragma unroll
  for (int i = 0; i < 32; i += 8)
    Wt[(size_t)(n0 + ty + i) * K + k0 + tx] = f2bf(tile[tx][ty + i]);
}

// Combined dt|B|C transposed weight: Wt[NEXT][DINNER] bf16.
// rows [0,2048) = dt_w^T, [2048,2064) = B_w^T, [2064,2080) = C_w^T, [2080,2112) = 0.
__global__ void build_w2t_k(const float* __restrict__ dt_w, const float* __restrict__ B_w,
                            const float* __restrict__ C_w, unsigned short* __restrict__ Wt) {
  __shared__ float tile[32][33];
  int k0 = blockIdx.x * 32, n0 = blockIdx.y * 32;
  int tx = threadIdx.x, ty = threadIdx.y;  // 32 x 8
  if (n0 < DINNER) {
#pragma unroll
    for (int i = 0; i < 32; i += 8)
      tile[ty + i][tx] = dt_w[(size_t)(k0 + ty + i) * DINNER + n0 + tx];
    __syncthreads();
#pragma unroll
    for (int i = 0; i < 32; i += 8)
      Wt[(size_t)(n0 + ty + i) * DINNER + k0 + tx] = f2bf(tile[tx][ty + i]);
  } else {
#pragma unroll
    for (int i = 0; i < 32; i += 8) {
      int n = n0 + ty + i;
      float v = 0.f;
      if (n < DINNER + 16) v = B_w[(size_t)(k0 + tx) * DSTATE + (n - DINNER)];
      else if (n < DINNER + 32) v = C_w[(size_t)(k0 + tx) * DSTATE + (n - DINNER - 16)];
      Wt[(size_t)n * DINNER + k0 + tx] = f2bf(v);
    }
  }
}

__global__ __launch_bounds__(256) void rmsnorm_k(const float* __restrict__ x,
                                                 const float* __restrict__ w,
                                                 unsigned short* __restrict__ xnbf) {
  int row = blockIdx.x, tid = threadIdx.x;
  const float4 v = *(const float4*)(x + (size_t)row * DMODEL + tid * 4);
  float ss = v.x * v.x + v.y * v.y + v.z * v.z + v.w * v.w;
#pragma unroll
  for (int off = 32; off > 0; off >>= 1) ss += __shfl_down(ss, off);
  __shared__ float red[4];
  if ((tid & 63) == 0) red[tid >> 6] = ss;
  __syncthreads();
  float tot = red[0] + red[1] + red[2] + red[3];
  float scale = rsqrtf(tot * (1.0f / DMODEL) + 1e-6f);
  const float4 wv = *(const float4*)(w + tid * 4);
  ushort4 o;
  o.x = f2bf(v.x * scale * wv.x);
  o.y = f2bf(v.y * scale * wv.y);
  o.z = f2bf(v.z * scale * wv.z);
  o.w = f2bf(v.w * scale * wv.w);
  *(ushort4*)(xnbf + (size_t)row * DMODEL + tid * 4) = o;
}

// C = A[M,K](bf16) @ Bt[N,K](bf16)^T, f32 out. BMxBN tile, BK=32, 4 waves (2x2).
// Double-buffered LDS, 1 barrier per K-step, XCD-swizzled block order.
// MODE 0: plain C[row*ldc+col].
// MODE 2: cols<DINNER -> softplus(+bias) into C (ldc=DINNER); cols DINNER..+16 -> Bm;
//         +16..+32 -> Cm; rest dropped.
template <int BM, int BN, int MODE>
__global__ __launch_bounds__(256) void gemm_bf16_t(const unsigned short* __restrict__ A,
                                                   const unsigned short* __restrict__ Bt,
                                                   float* __restrict__ C,
                                                   int M, int N, int K, int ldc,
                                                   const float* __restrict__ bias,
                                                   float* __restrict__ Bm,
                                                   float* __restrict__ Cm) {
  constexpr int WTM = BM / 2, WTN = BN / 2;
  constexpr int FM = WTM / 16, FN = WTN / 16;
  __shared__ __align__(16) unsigned short Abuf[2][BM * 32];
  __shared__ __align__(16) unsigned short Bbuf[2][BN * 32];
  const int tid = threadIdx.x;
  const int wave = tid >> 6, lane = tid & 63;

  // XCD-aware swizzle (grid size is a multiple of 8): contiguous output tiles per XCD.
  const int gx = gridDim.x;
  int lin = blockIdx.y * gx + blockIdx.x;
  int nwg = gx * gridDim.y;
  int swz = (lin & 7) * (nwg >> 3) + (lin >> 3);
  const int bm = (swz / gx) * BM, bn = (swz % gx) * BN;

  const int wm = wave >> 1, wn = wave & 1;
  const int lrow = lane & 15, lk = (lane >> 4) * 8;
  const int srow = lane >> 2, skoff = (lane & 3) * 8;

  const unsigned short* Ag = A + (size_t)(bm + wave * 16 + srow) * K + skoff;
  const unsigned short* Bg = Bt + (size_t)(bn + wave * 16 + srow) * K + skoff;

  auto stage = [&](int buf, int k0) {
#pragma unroll
    for (int r = 0; r < BM / 64; ++r)
      gload_lds16(Ag + (size_t)r * 64 * K + k0, &Abuf[buf][(r * 64 + wave * 16) * 32]);
#pragma unroll
    for (int r = 0; r < BN / 64; ++r)
      gload_lds16(Bg + (size_t)r * 64 * K + k0, &Bbuf[buf][(r * 64 + wave * 16) * 32]);
  };

  f32x4 acc[FM][FN] = {};
  const int nt = K / 32;
  stage(0, 0);
  __syncthreads();
  int cur = 0;
  for (int t = 0; t < nt; ++t) {
    if (t + 1 < nt) stage(cur ^ 1, (t + 1) * 32);
    short8 af[FM], bfr[FN];
#pragma unroll
    for (int m = 0; m < FM; ++m)
      af[m] = *(const short8*)&Abuf[cur][(wm * WTM + m * 16 + lrow) * 32 + lk];
#pragma unroll
    for (int n = 0; n < FN; ++n)
      bfr[n] = *(const short8*)&Bbuf[cur][(wn * WTN + n * 16 + lrow) * 32 + lk];
#pragma unroll
    for (int m = 0; m < FM; ++m)
#pragma unroll
      for (int n = 0; n < FN; ++n)
        acc[m][n] = __builtin_amdgcn_mfma_f32_16x16x32_bf16(af[m], bfr[n], acc[m][n], 0, 0, 0);
    __syncthreads();  // drains stage(t+1) vmem + guards dbuf WAR; 1 barrier/K-step
    cur ^= 1;
  }

  const int rbase = bm + wm * WTM + (lane >> 4) * 4;
  const int cbase = bn + wn * WTN + lrow;
#pragma unroll
  for (int m = 0; m < FM; ++m)
#pragma unroll
    for (int n = 0; n < FN; ++n) {
      int col = cbase + n * 16;
#pragma unroll
      for (int r = 0; r < 4; ++r) {
        int row = rbase + m * 16 + r;
        float v = acc[m][n][r];
        if (MODE == 0) {
          C[(size_t)row * ldc + col] = v;
        } else {  // MODE 2 (dt | B | C combined)
          if (col < DINNER)
            C[(size_t)row * DINNER + col] = softplus_f(v + bias[col]);
          else if (col < DINNER + 16)
            Bm[(size_t)row * DSTATE + (col - DINNER)] = v;
          else if (col < DINNER + 32)
            Cm[(size_t)row * DSTATE + (col - DINNER - 16)] = v;
        }
      }
    }
}

// Fused: x_inner = a * silu(g), then causal depthwise conv width 4. 8 t per thread.
__global__ __launch_bounds__(256) void siluconv_k(const float* __restrict__ xg,
                                                  const float* __restrict__ w,
                                                  float* __restrict__ xc,
                                                  unsigned short* __restrict__ xcbf) {
  int idx = blockIdx.x * 256 + threadIdx.x;
  int d4 = (idx & 511) << 2;
  int tc = (idx >> 9) & 127;
  int b = idx >> 16;
  float4 w0 = *(const float4*)(w + (d4 + 0) * 4);
  float4 w1 = *(const float4*)(w + (d4 + 1) * 4);
  float4 w2 = *(const float4*)(w + (d4 + 2) * 4);
  float4 w3 = *(const float4*)(w + (d4 + 3) * 4);
  const float wj0[4] = {w0.x, w0.y, w0.z, w0.w};
  const float wj1[4] = {w1.x, w1.y, w1.z, w1.w};
  const float wj2[4] = {w2.x, w2.y, w2.z, w2.w};
  const float wj3[4] = {w3.x, w3.y, w3.z, w3.w};
  const float* pa = xg + (size_t)b * SEQ * (2 * DINNER) + d4;
  const float* pg = pa + DINNER;
  int t0 = tc * 8;
  float4 sA = {0.f, 0.f, 0.f, 0.f}, sB = sA, sC = sA;
  auto gated = [&](int t) {
    float4 a = *(const float4*)(pa + (size_t)t * (2 * DINNER));
    float4 g = *(const float4*)(pg + (size_t)t * (2 * DINNER));
    float4 r;
    r.x = a.x * (g.x / (1.f + __expf(-g.x)));
    r.y = a.y * (g.y / (1.f + __expf(-g.y)));
    r.z = a.z * (g.z / (1.f + __expf(-g.z)));
    r.w = a.w * (g.w / (1.f + __expf(-g.w)));
    return r;
  };
  if (t0 > 0) {
    sA = gated(t0 - 3);
    sB = gated(t0 - 2);
    sC = gated(t0 - 1);
  }
#pragma unroll
  for (int j = 0; j < 8; ++j) {
    int t = t0 + j;
    float4 sD = gated(t);
    float4 o;
    o.x = sA.x * wj0[0] + sB.x * wj0[1] + sC.x * wj0[2] + sD.x * wj0[3];
    o.y = sA.y * wj1[0] + sB.y * wj1[1] + sC.y * wj1[2] + sD.y * wj1[3];
    o.z = sA.z * wj2[0] + sB.z * wj2[1] + sC.z * wj2[2] + sD.z * wj2[3];
    o.w = sA.w * wj3[0] + sB.w * wj3[1] + sC.w * wj3[2] + sD.w * wj3[3];
    size_t ro = ((size_t)(b * SEQ + t)) * DINNER + d4;
    *(float4*)(xc + ro) = o;
    ushort4 ob = {f2bf(o.x), f2bf(o.y), f2bf(o.z), f2bf(o.w)};
    *(ushort4*)(xcbf + ro) = ob;
    sA = sB; sB = sC; sC = sD;
  }
}

__global__ __launch_bounds__(256) void scan_local_k(const float* __restrict__ dt,
                                                    const float* __restrict__ xc,
                                                    const float* __restrict__ Bm,
                                                    const float* __restrict__ A,
                                                    float* __restrict__ hfin,
                                                    float* __restrict__ P) {
  int d = blockIdx.x * 256 + threadIdx.x;
  int c = blockIdx.y, b = blockIdx.z;
  float a[DSTATE], h[DSTATE];
#pragma unroll
  for (int s = 0; s < DSTATE; ++s) { a[s] = A[(size_t)d * DSTATE + s]; h[s] = 0.f; }
  float sdt = 0.f;
  int t0 = c * CLEN;
  for (int t = t0; t < t0 + CLEN; ++t) {
    size_t ro = (size_t)(b * SEQ + t);
    float dtv = dt[ro * DINNER + d];
    float xv = xc[ro * DINNER + d];
    sdt += dtv;
    float bx = dtv * xv;
    float4 q0 = *(const float4*)(Bm + ro * DSTATE + 0);
    float4 q1 = *(const float4*)(Bm + ro * DSTATE + 4);
    float4 q2 = *(const float4*)(Bm + ro * DSTATE + 8);
    float4 q3 = *(const float4*)(Bm + ro * DSTATE + 12);
    float bm[DSTATE] = {q0.x, q0.y, q0.z, q0.w, q1.x, q1.y, q1.z, q1.w,
                        q2.x, q2.y, q2.z, q2.w, q3.x, q3.y, q3.z, q3.w};
#pragma unroll
    for (int s = 0; s < DSTATE; ++s) {
      float av = __expf(a[s] * dtv);
      h[s] = fmaf(av, h[s], bx * bm[s]);
    }
  }
  size_t o = ((size_t)(b * NCHUNK + c) * DINNER + d) * DSTATE;
#pragma unroll
  for (int s = 0; s < DSTATE; ++s) {
    hfin[o + s] = h[s];
    P[o + s] = __expf(a[s] * sdt);
  }
}

__global__ __launch_bounds__(256) void scan_chunks_k(const float* __restrict__ hfin,
                                                     const float* __restrict__ P,
                                                     float* __restrict__ Hprev) {
  int j = blockIdx.x * 256 + threadIdx.x;
  int b = j / (DINNER * DSTATE);
  int r = j % (DINNER * DSTATE);
  float H = 0.f;
  for (int c = 0; c < NCHUNK; ++c) {
    size_t o = ((size_t)(b * NCHUNK + c) * DINNER * DSTATE) + r;
    Hprev[o] = H;
    H = fmaf(P[o], H, hfin[o]);
  }
}

__global__ __launch_bounds__(256) void scan_final_k(const float* __restrict__ dt,
                                                    const float* __restrict__ xc,
                                                    const float* __restrict__ Bm,
                                                    const float* __restrict__ Cm,
                                                    const float* __restrict__ A,
                                                    const float* __restrict__ Hprev,
                                                    const float* __restrict__ Dskip,
                                                    unsigned short* __restrict__ ysbf) {
  int d = blockIdx.x * 256 + threadIdx.x;
  int c = blockIdx.y, b = blockIdx.z;
  float a[DSTATE], h[DSTATE];
  size_t ho = ((size_t)(b * NCHUNK + c) * DINNER + d) * DSTATE;
#pragma unroll
  for (int s = 0; s < DSTATE; ++s) {
    a[s] = A[(size_t)d * DSTATE + s];
    h[s] = Hprev[ho + s];
  }
  float Dv = Dskip[d];
  int t0 = c * CLEN;
  for (int t = t0; t < t0 + CLEN; ++t) {
    size_t ro = (size_t)(b * SEQ + t);
    float dtv = dt[ro * DINNER + d];
    float xv = xc[ro * DINNER + d];
    float bx = dtv * xv;
    float4 q0 = *(const float4*)(Bm + ro * DSTATE + 0);
    float4 q1 = *(const float4*)(Bm + ro * DSTATE + 4);
    float4 q2 = *(const float4*)(Bm + ro * DSTATE + 8);
    float4 q3 = *(const float4*)(Bm + ro * DSTATE + 12);
    float bm[DSTATE] = {q0.x, q0.y, q0.z, q0.w, q1.x, q1.y, q1.z, q1.w,
                        q2.x, q2.y, q2.z, q2.w, q3.x, q3.y, q3.z, q3.w};
    float4 r0 = *(const float4*)(Cm + ro * DSTATE + 0);
    float4 r1 = *(const float4*)(Cm + ro * DSTATE + 4);
    float4 r2 = *(const float4*)(Cm + ro * DSTATE + 8);
    float4 r3 = *(const float4*)(Cm + ro * DSTATE + 12);
    float cm[DSTATE] = {r0.x, r0.y, r0.z, r0.w, r1.x, r1.y, r1.z, r1.w,
                        r2.x, r2.y, r2.z, r2.w, r3.x, r3.y, r3.z, r3.w};
    float y = Dv * xv;
#pragma unroll
    for (int s = 0; s < DSTATE; ++s) {
      float av = __expf(a[s] * dtv);
      h[s] = fmaf(av, h[s], bx * bm[s]);
      y = fmaf(h[s], cm[s], y);
    }
    ysbf[ro * DINNER + d] = f2bf(y);
  }
}

extern "C" void kernel_launch(void* const* d_in, const int* in_sizes, int n_in,
                              void* d_out, int out_size, void* d_ws, size_t ws_size,
                              hipStream_t stream) {
  (void)in_sizes; (void)n_in; (void)out_size; (void)ws_size;
  const float* x       = (const float*)d_in[0];
  const float* norm_w  = (const float*)d_in[1];
  const float* in_proj = (const float*)d_in[2];
  const float* conv_w  = (const float*)d_in[3];
  const float* dt_w    = (const float*)d_in[4];
  const float* dt_b    = (const float*)d_in[5];
  const float* A_log   = (const float*)d_in[6];
  const float* B_w     = (const float*)d_in[7];
  const float* C_w     = (const float*)d_in[8];
  const float* D_skip  = (const float*)d_in[9];
  const float* out_w   = (const float*)d_in[10];
  float* out = (float*)d_out;
  float* ws = (float*)d_ws;

  // Workspace (f32 units), lifetime-aliased:
  float* Aneg = ws;                  // 32768
  float* Bm   = ws + 32768;
  float* Cm   = ws + 65536;
  float* RA   = ws + 98304;          // 2.1M f32: in_wT -> W2t(1.06M) -> Hprev(1.05M)
  float* RB   = RA + 2097152;        // 1.05M f32: xn_bf -> out_wT
  float* RC   = RB + 1048576;        // 8.39M f32: xg -> dtb(4.19M)+hfin(2.1M)+P(2.1M)
  float* RD   = RC + 8388608;        // 4.19M f32: xc
  float* RE   = RD + 4194304;        // 2.1M f32: xc_bf -> ys_bf
  unsigned short* in_wT  = (unsigned short*)RA;
  unsigned short* W2t    = (unsigned short*)RA;
  float*          Hprev  = RA;
  unsigned short* xn_bf  = (unsigned short*)RB;
  unsigned short* out_wT = (unsigned short*)RB;
  float* xg   = RC;
  float* dtb  = RC;
  float* hfin = RC + 4194304;
  float* Pbuf = RC + 6291456;
  float* xc   = RD;
  unsigned short* xc_bf = (unsigned short*)RE;
  unsigned short* ys_bf = (unsigned short*)RE;

  init_aneg_k<<<dim3(DINNER * DSTATE / 256), dim3(256), 0, stream>>>(A_log, Aneg);
  transpose_cvt_k<<<dim3(2 * DINNER / 32, DMODEL / 32), dim3(32, 8), 0, stream>>>(
      in_proj, in_wT, DMODEL, 2 * DINNER);
  rmsnorm_k<<<dim3(NTOK), dim3(256), 0, stream>>>(x, norm_w, xn_bf);
  gemm_bf16_t<128, 128, 0><<<dim3(2 * DINNER / 128, NTOK / 128), dim3(256), 0, stream>>>(
      xn_bf, in_wT, xg, NTOK, 2 * DINNER, DMODEL, 2 * DINNER, nullptr, nullptr, nullptr);
  siluconv_k<<<dim3(NTOK * (DINNER / 4) / 8 / 256), dim3(256), 0, stream>>>(
      xg, conv_w, xc, xc_bf);
  build_w2t_k<<<dim3(DINNER / 32, NEXT / 32), dim3(32, 8), 0, stream>>>(
      dt_w, B_w, C_w, W2t);
  gemm_bf16_t<128, 64, 2><<<dim3(NEXT / 64, NTOK / 128), dim3(256), 0, stream>>>(
      xc_bf, W2t, dtb, NTOK, NEXT, DINNER, DINNER, dt_b, Bm, Cm);
  scan_local_k<<<dim3(DINNER / 256, NCHUNK, BATCH), dim3(256), 0, stream>>>(
      dtb, xc, Bm, Aneg, hfin, Pbuf);
  scan_chunks_k<<<dim3(BATCH * DINNER * DSTATE / 256), dim3(256), 0, stream>>>(
      hfin, Pbuf, Hprev);
  scan_final_k<<<dim3(DINNER / 256, NCHUNK, BATCH), dim3(256), 0, stream>>>(
      dtb, xc, Bm, Cm, Aneg, Hprev, D_skip, ys_bf);
  transpose_cvt_k<<<dim3(DMODEL / 32, DINNER / 32), dim3(32, 8), 0, stream>>>(
      out_w, out_wT, DINNER, DMODEL);
  gemm_bf16_t<64, 64, 0><<<dim3(DMODEL / 64, NTOK / 64), dim3(256), 0, stream>>>(
      ys_bf, out_wT, out, NTOK, DMODEL, DINNER, DMODEL, nullptr, nullptr, nullptr);
}